// Round 7
// baseline (8561.468 us; speedup 1.0000x reference)
//
#include <hip/hip_runtime.h>
#include <math.h>

// stacked_rnn R7: persistent cooperative kernel, weights LDS-resident,
// ZERO per-epoch fences. h-exchange: relaxed agent atomic stores (proven,
// LLC write-through before vmcnt0-drained flag) + relaxed agent atomic loads
// (LLC-coherent read path). R5's failure was the UN-FENCED plain-load FC
// reading stale L1/L2 (absmax 7e-2 = "bias only") -- fixed here with one
// wave0 acquire fence AFTER the loop, before FC. x/weights/bias stay hot in
// L1/L2 forever (nothing invalidates them anymore).

typedef __bf16 bf16;
typedef __bf16 bf16x8 __attribute__((ext_vector_type(8)));
typedef float floatx4 __attribute__((ext_vector_type(4)));
typedef unsigned long long ull;

#define B_   128
#define T_   256
#define H_   1024
#define I_   150
#define KX_  160
#define C_   60
#define K1LDS 1280   // layer-1 LDS row width in elems
#define K2LDS 2048   // layer-2 LDS row width
#define NLINES 16    // counter lines
#define CSTRIDE 64   // uints between lines (256B)

template<int N> struct IC { static constexpr int value = N; };

__device__ __forceinline__ float sigmoidf_(float x) { return 1.f / (1.f + expf(-x)); }

union u2bf8 { ull u[2]; bf16x8 v; };

// ---------------- conversion / init kernel ----------------
__global__ __launch_bounds__(256)
void convert_all(const float* __restrict__ x,
                 const float* __restrict__ h1in, const float* __restrict__ h2in,
                 bf16* __restrict__ xb, bf16* __restrict__ h1b0, bf16* __restrict__ h2b0,
                 unsigned* __restrict__ cnt)
{
    const size_t nXB = (size_t)T_ * B_ * KX_;   // 5242880
    const size_t nHC = (size_t)B_ * H_;         // 131072
    size_t idx = (size_t)blockIdx.x * 256 + threadIdx.x;

    if (idx < nXB) {                            // x [B][T][150] -> xb [T][B][160]
        size_t t = idx / (B_ * KX_);
        size_t r = idx - t * (B_ * KX_);
        size_t b = r / KX_, k = r - b * KX_;
        xb[idx] = (k < I_) ? (bf16)x[(b * T_ + t) * I_ + k] : (bf16)0.f;
        return;
    }
    idx -= nXB;
    if (idx < nHC) { h1b0[idx] = (bf16)h1in[idx]; return; }
    idx -= nHC;
    if (idx < nHC) { h2b0[idx] = (bf16)h2in[idx]; return; }
    idx -= nHC;
    if (idx < NLINES * CSTRIDE) cnt[idx] = 0u;
}

// ---------------- persistent LSTM kernel ----------------
// NCOLS=32 -> 256 blocks/128KiB LDS; NCOLS=16 -> 512 blocks/64KiB LDS.
// layer = (bid>>3)&1, slice = (bid&7)|((bid>>4)<<3).
// cnt lines 0..7: arrival counters by (bid&7). line 8: epoch broadcast flag.
template<int NCOLS>
__global__ __launch_bounds__(256, 1)
void rnn_persistent(const bf16* __restrict__ xb,
                    bf16* __restrict__ h1b0, bf16* __restrict__ h1b1,
                    bf16* __restrict__ h2b0, bf16* __restrict__ h2b1,
                    const float* __restrict__ c1in, const float* __restrict__ c2in,
                    const float* __restrict__ Wih1, const float* __restrict__ Whh1,
                    const float* __restrict__ bih1, const float* __restrict__ bhh1,
                    const float* __restrict__ Wih2, const float* __restrict__ Whh2,
                    const float* __restrict__ bih2, const float* __restrict__ bhh2,
                    const float* __restrict__ Wfc, const float* __restrict__ bfc,
                    float* __restrict__ out, unsigned* __restrict__ cnt, int nblk)
{
    constexpr int NHC = NCOLS / 4;      // h-cols per block
    constexpr int NT  = NCOLS / 16;     // N-tiles (2 or 1)
    constexpr int GPR = NHC / 4;        // 8B col-groups per row (2 or 1)
    extern __shared__ bf16 lds[];
    __shared__ __align__(16) bf16 hst[4][32][NHC];   // epilogue staging

    const int tid   = threadIdx.x;
    const int bid   = blockIdx.x;
    const int layer = (bid >> 3) & 1;
    const int slice = (bid & 7) | ((bid >> 4) << 3);
    const int n0h   = slice * NHC;
    const int KLDS  = layer ? K2LDS : K1LDS;
    const int arr_per_line = nblk >> 3;

    // ---- stage weights fp32->bf16 into swizzled LDS (once) ----
    {
        const int cpr = KLDS >> 3;              // 16B chunks per row
        const int total = NCOLS * cpr;
        for (int ci = tid; ci < total; ci += 256) {
            int r = ci / cpr, c = ci - r * cpr;
            int g = r / NHC, j = r - g * NHC;
            int grow = (g << 10) + n0h + j;
            int k0 = c << 3;
            float v[8];
#pragma unroll
            for (int u = 0; u < 8; ++u) {
                int k = k0 + u;
                if (layer == 0)
                    v[u] = (k < I_) ? Wih1[(size_t)grow * I_ + k]
                         : (k < KX_) ? 0.f
                         : (k < KX_ + H_) ? Whh1[(size_t)grow * H_ + (k - KX_)] : 0.f;
                else
                    v[u] = (k < H_) ? Wih2[(size_t)grow * H_ + k]
                                    : Whh2[(size_t)grow * H_ + (k - H_)];
            }
            int cs = (c & ~15) | ((c ^ r) & 15);      // XOR swizzle
            bf16* dst = lds + (size_t)r * KLDS + (cs << 3);
#pragma unroll
            for (int u = 0; u < 8; ++u) dst[u] = (bf16)v[u];
        }
    }
    __syncthreads();

    const int lane = tid & 63;
    const int wv   = tid >> 6;
    const int jj   = lane & (NHC - 1);
    const int quad = lane >> 4;

    float4 bias;
    {
        const float* bi = layer ? bih2 : bih1;
        const float* bh = layer ? bhh2 : bhh1;
        int col = n0h + jj;
        bias.x = bi[col] + bh[col];
        bias.y = bi[col + H_] + bh[col + H_];
        bias.z = bi[col + 2 * H_] + bh[col + 2 * H_];
        bias.w = bi[col + 3 * H_] + bh[col + 3 * H_];
    }

    float creg[4];
    {
        const float* cin = layer ? c2in : c1in;
        if constexpr (NCOLS == 32) {
            int dup = (lane >> 3) & 1;
#pragma unroll
            for (int t = 0; t < 2; ++t)
#pragma unroll
                for (int rp = 0; rp < 2; ++rp) {
                    int r = rp * 2 + dup;
                    int row = wv * 32 + t * 16 + quad * 4 + r;
                    creg[t * 2 + rp] = cin[(size_t)row * H_ + n0h + jj];
                }
        } else {
            int r = (lane >> 2) & 3;
#pragma unroll
            for (int t = 0; t < 2; ++t) {
                int row = wv * 32 + t * 16 + quad * 4 + r;
                creg[t] = cin[(size_t)row * H_ + n0h + jj];
            }
        }
    }

    floatx4 acc[2][NT];

    // x-segment: plain cached vectorized loads (x never changes; L2 stays hot)
    auto seg_x = [&](const bf16* A, int ldA, auto nksC, int ksBase) {
        constexpr int NKS = decltype(nksC)::value;
        const int arow = wv * 32 + (lane & 15);
        const bf16* a0 = A + (size_t)arow * ldA + quad * 8;
        const bf16* a1 = a0 + 16 * ldA;
        bf16x8 a0r[NKS], a1r[NKS];
#pragma unroll
        for (int i = 0; i < NKS; ++i) {
            a0r[i] = *(const bf16x8*)(a0 + i * 32);
            a1r[i] = *(const bf16x8*)(a1 + i * 32);
        }
#pragma unroll
        for (int i = 0; i < NKS; ++i) {
            int c = (ksBase + i) * 4 + quad;
#pragma unroll
            for (int t = 0; t < NT; ++t) {
                int r = t * 16 + (lane & 15);
                int cs = (c & ~15) | ((c ^ r) & 15);
                bf16x8 bfr = *(const bf16x8*)(lds + (size_t)r * KLDS + (cs << 3));
                acc[0][t] = __builtin_amdgcn_mfma_f32_16x16x32_bf16(a0r[i], bfr, acc[0][t], 0, 0, 0);
                acc[1][t] = __builtin_amdgcn_mfma_f32_16x16x32_bf16(a1r[i], bfr, acc[1][t], 0, 0, 0);
            }
        }
    };

    // h-segment: relaxed agent atomic 8B loads (LLC-coherent), chunked 8 ksteps
    // (32 outstanding loads/wave) to cover LLC latency.
    auto seg_h = [&](const bf16* A, auto nksC, int ksBase) {
        constexpr int NKS = decltype(nksC)::value;
        constexpr int CH  = 8;
        const int arow = wv * 32 + (lane & 15);
        const ull* a0 = (const ull*)(A + (size_t)arow * H_ + quad * 8);
        const ull* a1 = (const ull*)(A + (size_t)(arow + 16) * H_ + quad * 8);
        for (int blk = 0; blk < NKS; blk += CH) {
            ull r0[CH][2], r1[CH][2];
#pragma unroll
            for (int i = 0; i < CH; ++i) {
                const ull* p0 = a0 + (size_t)(blk + i) * 8;   // kstep = 32 bf16 = 8 ull
                const ull* p1 = a1 + (size_t)(blk + i) * 8;
                r0[i][0] = __hip_atomic_load(p0,     __ATOMIC_RELAXED, __HIP_MEMORY_SCOPE_AGENT);
                r0[i][1] = __hip_atomic_load(p0 + 1, __ATOMIC_RELAXED, __HIP_MEMORY_SCOPE_AGENT);
                r1[i][0] = __hip_atomic_load(p1,     __ATOMIC_RELAXED, __HIP_MEMORY_SCOPE_AGENT);
                r1[i][1] = __hip_atomic_load(p1 + 1, __ATOMIC_RELAXED, __HIP_MEMORY_SCOPE_AGENT);
            }
#pragma unroll
            for (int i = 0; i < CH; ++i) {
                u2bf8 f0, f1;
                f0.u[0] = r0[i][0]; f0.u[1] = r0[i][1];
                f1.u[0] = r1[i][0]; f1.u[1] = r1[i][1];
                int c = (ksBase + blk + i) * 4 + quad;
#pragma unroll
                for (int t = 0; t < NT; ++t) {
                    int r = t * 16 + (lane & 15);
                    int cs = (c & ~15) | ((c ^ r) & 15);
                    bf16x8 bfr = *(const bf16x8*)(lds + (size_t)r * KLDS + (cs << 3));
                    acc[0][t] = __builtin_amdgcn_mfma_f32_16x16x32_bf16(f0.v, bfr, acc[0][t], 0, 0, 0);
                    acc[1][t] = __builtin_amdgcn_mfma_f32_16x16x32_bf16(f1.v, bfr, acc[1][t], 0, 0, 0);
                }
            }
        }
    };

    for (int e = 0; e <= T_; ++e) {
        const bool active = layer == 0 ? (e < T_) : (e >= 1);
        if (active) {
#pragma unroll
            for (int t = 0; t < 2; ++t)
#pragma unroll
                for (int u = 0; u < NT; ++u) acc[t][u] = (floatx4){0.f, 0.f, 0.f, 0.f};

            const bf16* h1r = (e & 1) ? h1b1 : h1b0;         // h1^(e)
            if (layer == 0) {
                const bf16* xt = xb + (size_t)e * B_ * KX_;
                seg_x(xt, KX_, IC<5>{}, 0);
                seg_h(h1r, IC<32>{}, 5);
            } else {
                const bf16* h2r = (e & 1) ? h2b0 : h2b1;     // h2^(e-1)
                seg_h(h1r, IC<32>{}, 0);
                seg_h(h2r, IC<32>{}, 32);
            }
            bf16* hw = (layer == 0) ? ((e & 1) ? h1b0 : h1b1)   // h1^(e+1)
                                    : ((e & 1) ? h2b1 : h2b0);  // h2^(e)

            // epilogue: shfl-gather gates, update creg, stage h to LDS
            const int base = lane & 48;
#pragma unroll
            for (int t = 0; t < 2; ++t) {
#pragma unroll
                for (int r = 0; r < 4; ++r) {
                    float vi, vf, vg, vo;
                    if constexpr (NCOLS == 32) {
                        vi = __shfl(acc[t][0][r], base + jj, 64);
                        vf = __shfl(acc[t][0][r], base + 8 + jj, 64);
                        vg = __shfl(acc[t][1][r], base + jj, 64);
                        vo = __shfl(acc[t][1][r], base + 8 + jj, 64);
                    } else {
                        vi = __shfl(acc[t][0][r], base + jj, 64);
                        vf = __shfl(acc[t][0][r], base + 4 + jj, 64);
                        vg = __shfl(acc[t][0][r], base + 8 + jj, 64);
                        vo = __shfl(acc[t][0][r], base + 12 + jj, 64);
                    }
                    bool cond; int slot;
                    if constexpr (NCOLS == 32) {
                        cond = (((lane >> 3) & 1) == (r & 1));
                        slot = t * 2 + (r >> 1);
                    } else {
                        cond = (((lane >> 2) & 3) == r);
                        slot = t;
                    }
                    if (cond) {
                        float cv = creg[slot];
                        float cn = sigmoidf_(vf + bias.y) * cv
                                 + sigmoidf_(vi + bias.x) * tanhf(vg + bias.z);
                        creg[slot] = cn;
                        float hn = sigmoidf_(vo + bias.w) * tanhf(cn);
                        hst[wv][t * 16 + quad * 4 + r][jj] = (bf16)hn;
                    }
                }
            }
            __syncthreads();
            // vectorized 8B relaxed-agent atomic stores (LLC write-through)
            if (lane < 32 * GPR) {
                int row_l = lane / GPR, cg = lane - row_l * GPR;
                ull v = *(const ull*)&hst[wv][row_l][cg * 4];
                __hip_atomic_store((ull*)(hw + (size_t)(wv * 32 + row_l) * H_ + n0h + cg * 4),
                                   v, __ATOMIC_RELAXED, __HIP_MEMORY_SCOPE_AGENT);
            }
        }

        // ---- two-level barrier: RMW lines (0..7) + broadcast flag line (8) ----
        asm volatile("s_waitcnt vmcnt(0)" ::: "memory");   // h stores reached LLC
        __syncthreads();
        const unsigned etag = (unsigned)(e + 1);
        if (bid == 0) {
            if (tid == 0)
                __hip_atomic_fetch_add(cnt, 1u, __ATOMIC_RELAXED, __HIP_MEMORY_SCOPE_AGENT);
            if (tid < 8) {
                const unsigned tgt = etag * (unsigned)arr_per_line;
                const unsigned* cp = cnt + tid * CSTRIDE;
                while (__hip_atomic_load(cp, __ATOMIC_RELAXED, __HIP_MEMORY_SCOPE_AGENT) < tgt)
                    __builtin_amdgcn_s_sleep(1);
            }
            if (tid == 0)
                __hip_atomic_store(cnt + 8 * CSTRIDE, etag,
                                   __ATOMIC_RELAXED, __HIP_MEMORY_SCOPE_AGENT);
        } else {
            if (tid == 0) {
                __hip_atomic_fetch_add(cnt + (bid & 7) * CSTRIDE, 1u,
                                       __ATOMIC_RELAXED, __HIP_MEMORY_SCOPE_AGENT);
                const unsigned* fp = cnt + 8 * CSTRIDE;
                while (__hip_atomic_load(fp, __ATOMIC_RELAXED, __HIP_MEMORY_SCOPE_AGENT) < etag)
                    __builtin_amdgcn_s_sleep(1);
            }
        }
        __syncthreads();
        // NO per-epoch fence: h reads are LLC-coherent atomic loads; cached
        // data (x, weights, biases) is immutable for the whole kernel.
    }

    // one acquire fence (wave0 only: invalidates this CU's L1 + XCD L2) so the
    // plain-load FC below sees the final h2 -- THE fix for R5's failure.
    if (tid < 64)
        __builtin_amdgcn_fence(__ATOMIC_ACQUIRE, "agent");
    __syncthreads();

    // ---- fused FC: out = h2^(256) @ Wfc^T + bfc ; h2^(256) is in h2b0 ----
    if (bid < B_) {
        const bf16* h2f = h2b0;
        for (int c = wv; c < C_; c += 4) {
            float a = 0.f;
            for (int k = lane; k < H_; k += 64)
                a += (float)h2f[(size_t)bid * H_ + k] * Wfc[(size_t)c * H_ + k];
#pragma unroll
            for (int off = 32; off; off >>= 1) a += __shfl_down(a, off, 64);
            if (lane == 0) out[bid * C_ + c] = a + bfc[c];
        }
    }
}

extern "C" void kernel_launch(void* const* d_in, const int* in_sizes, int n_in,
                              void* d_out, int out_size, void* d_ws, size_t ws_size,
                              hipStream_t stream)
{
    const float* x    = (const float*)d_in[0];
    const float* h1in = (const float*)d_in[1];
    const float* c1in = (const float*)d_in[2];
    const float* h2in = (const float*)d_in[3];
    const float* c2in = (const float*)d_in[4];
    const float* Wih1 = (const float*)d_in[5];
    const float* Whh1 = (const float*)d_in[6];
    const float* bih1 = (const float*)d_in[7];
    const float* bhh1 = (const float*)d_in[8];
    const float* Wih2 = (const float*)d_in[9];
    const float* Whh2 = (const float*)d_in[10];
    const float* bih2 = (const float*)d_in[11];
    const float* bhh2 = (const float*)d_in[12];
    const float* Wfc  = (const float*)d_in[13];
    const float* bfc  = (const float*)d_in[14];
    float* out = (float*)d_out;

    // ws carve (~11.5 MB)
    char* p = (char*)d_ws;
    bf16* xb = (bf16*)p;    p += (size_t)T_ * B_ * KX_ * 2;
    bf16* h1b0 = (bf16*)p;  p += (size_t)B_ * H_ * 2;
    bf16* h1b1 = (bf16*)p;  p += (size_t)B_ * H_ * 2;
    bf16* h2b0 = (bf16*)p;  p += (size_t)B_ * H_ * 2;
    bf16* h2b1 = (bf16*)p;  p += (size_t)B_ * H_ * 2;
    unsigned* cnt = (unsigned*)p;       // 16 lines x 256B

    const size_t citems = (size_t)T_ * B_ * KX_ + 2 * (size_t)B_ * H_ + NLINES * CSTRIDE;
    convert_all<<<(int)((citems + 255) / 256), 256, 0, stream>>>(
        x, h1in, h2in, xb, h1b0, h2b0, cnt);

    int nblk32 = 256, nblk16 = 512;
    void* args32[] = { &xb, &h1b0, &h1b1, &h2b0, &h2b1, (void*)&c1in, (void*)&c2in,
                       (void*)&Wih1, (void*)&Whh1, (void*)&bih1, (void*)&bhh1,
                       (void*)&Wih2, (void*)&Whh2, (void*)&bih2, (void*)&bhh2,
                       (void*)&Wfc, (void*)&bfc, &out, &cnt, &nblk32 };
    void* args16[] = { &xb, &h1b0, &h1b1, &h2b0, &h2b1, (void*)&c1in, (void*)&c2in,
                       (void*)&Wih1, (void*)&Whh1, (void*)&bih1, (void*)&bhh1,
                       (void*)&Wih2, (void*)&Whh2, (void*)&bih2, (void*)&bhh2,
                       (void*)&Wfc, (void*)&bfc, &out, &cnt, &nblk16 };

    (void)hipFuncSetAttribute((const void*)rnn_persistent<32>,
                              hipFuncAttributeMaxDynamicSharedMemorySize, 131072);
    hipError_t err = hipLaunchCooperativeKernel((const void*)rnn_persistent<32>,
                                                dim3(256), dim3(256), args32,
                                                131072u, stream);
    if (err != hipSuccess) {
        (void)hipGetLastError();
        (void)hipFuncSetAttribute((const void*)rnn_persistent<16>,
                                  hipFuncAttributeMaxDynamicSharedMemorySize, 65536);
        (void)hipLaunchCooperativeKernel((const void*)rnn_persistent<16>,
                                         dim3(512), dim3(256), args16,
                                         65536u, stream);
    }
}